// Round 11
// baseline (151.517 us; speedup 1.0000x reference)
//
#include <hip/hip_runtime.h>
#include <hip/hip_bf16.h>

#define N_NODES 100000
#define N_EDGES 800000
#define HIDDEN 128
#define NGROUPS 6250            // 100000 / 16 nodes per wave-group
#define PC_BLOCKS 1280          // 5 blocks/CU (32 KB LDS, ~80 regs), mult of 8 XCDs
#define BSLOTS 3126             // 2 halves x ceil(6250/4 groups per block)

typedef short frag_ab __attribute__((ext_vector_type(8)));   // 8 x bf16
typedef float frag_cd __attribute__((ext_vector_type(4)));   // 4 x f32

// round-to-nearest-even fp32 -> bf16 (scalar)
__device__ inline unsigned f2b(float f) {
    union { float f; unsigned u; } x; x.f = f;
    return (x.u + 0x7fffu + ((x.u >> 16) & 1u)) >> 16;
}

// packed pair fp32 -> bf16x2 (v_cvt_pk_bf16_f32 on gfx950)
__device__ inline unsigned pk2(float x, float y) {
    union { __hip_bfloat162 h; unsigned u; } c;
    c.h = __float22bfloat162_rn(make_float2(x, y));
    return c.u;
}

// ---------------------------------------------------------------------------
// Kernel 0 (R20 new): z fp32 -> bf16 (RNE, bit-identical to the pk2 path the
// GEMM used in-loop). Purpose: the GEMM's cur[8] fp32 staging was 32 VGPRs,
// pinning total live state at ~140 -> 2 waves/SIMD in R11..R19 (R19 counters:
// VGPR 108 + 32 AGPR, occ 16.8%). Pre-converting removes those regs entirely.
// 3.2M float4 reads / uint2 writes, perfectly coalesced; ~13 us HBM-bound;
// also leaves z_bf16 (25.6 MB) L3-warm for the GEMM.
// ---------------------------------------------------------------------------
__global__ __launch_bounds__(256) void zcvt(
    const float4* __restrict__ z4, uint2* __restrict__ zbf)
{
    const int i = blockIdx.x * 256 + threadIdx.x;   // < 3,200,000 exactly
    float4 v = z4[i];
    zbf[i] = make_uint2(pk2(v.x, v.y), pk2(v.z, v.w));
}

// ---------------------------------------------------------------------------
// Kernel 1 (MFMA GEMM, fused W-transpose): UV = z @ [W1src|W1dst] + [b1|0]
// -> uint8 + per-node-half scales.
// R20 = R18 structure (256-thr blocks, feature dim split across blocks:
// even block = U half, odd = V half; 32 KB half-W LDS; zero steady-state
// barriers) + zf loaded DIRECTLY from pre-converted z_bf16 (4 dwordx4/lane).
// Per-wave live state ~80 regs (acc 32 + zf 16 + addr) -> 5 blocks/CU
// (LDS 160/32 and regs both allow 5) = 20 waves/CU, vs R19's 8.
// K-loop / C-layout / quant math bit-identical per element to R16/R18/R19
// (absmax must stay 0.008789062). Persistent slot scheme from R18: stride
// 1280 is even so a block's half (and its staged LDS) never changes.
// ---------------------------------------------------------------------------
__global__ __launch_bounds__(256) void precompute_uv_mfma(
    const unsigned short* __restrict__ zbf, const float* __restrict__ W1,
    const float* __restrict__ b1, unsigned char* __restrict__ UVq,
    float* __restrict__ scales)
{
    __shared__ unsigned short smem[2048 * 8];        // 32 KB: W half, chunk-major [s][row]
    const int t = threadIdx.x;
    const int lane = t & 63;
    const int w = t >> 6;                            // 0..3
    const int g  = lane >> 4;
    const int lc = lane & 15;
    const int half = blockIdx.x & 1;                 // 0 = U (features 0-127), 1 = V
    const int roff = half * 128;                     // W1 k-row offset of this half

    // --- one-time stage: transpose+convert this half of W1 (128x128 f32)
    //     -> LDS frag[s*128 + r], s = 16B k-chunk (0..15), r = feature row.
    //     At fixed (s,p): 128 consecutive cols across threads -> coalesced. ---
    {
        const int r = t & 127;                       // feature row within half
        const int j = t >> 7;                        // 0/1: which 8 chunks
        #pragma unroll
        for (int sl = 0; sl < 8; ++sl) {
            const int s = j * 8 + sl;
            unsigned u[4];
            #pragma unroll
            for (int p = 0; p < 4; ++p) {
                float f0 = W1[(size_t)(roff + s * 8 + p * 2)     * HIDDEN + r];
                float f1 = W1[(size_t)(roff + s * 8 + p * 2 + 1) * HIDDEN + r];
                u[p] = f2b(f0) | (f2b(f1) << 16);
            }
            *(uint4*)&smem[(size_t)(s * 128 + r) * 8] = make_uint4(u[0], u[1], u[2], u[3]);
        }
    }
    __syncthreads();                                  // the only barrier

    const float4* b1f4 = (const float4*)b1;
    const frag_ab* wlds = (const frag_ab*)smem;

    int bslot = blockIdx.x;
    while (bslot < BSLOTS) {
        const int ng = (bslot >> 1) * 4 + w;          // node-group for this wave
        if (ng < NGROUPS) {
            const int node = ng * 16 + lc;

            // --- zf direct from z_bf16: lane (g,lc), q -> 16 B dwordx4 at
            //     zbf[node*128 + q*32 + g*8]. 4 independent loads, L3-warm. ---
            const unsigned short* zrow = zbf + (size_t)node * 128;
            frag_ab zf[4];
            #pragma unroll
            for (int q = 0; q < 4; ++q)
                zf[q] = *(const frag_ab*)(zrow + q * 32 + g * 8);

            // --- K loop: 32 ds_read_b128 + 32 MFMA (A = W half from LDS) ---
            frag_cd acc[8];
            #pragma unroll
            for (int mt = 0; mt < 8; ++mt)
                acc[mt] = (frag_cd){0.f, 0.f, 0.f, 0.f};
            #pragma unroll
            for (int q = 0; q < 4; ++q) {
                #pragma unroll
                for (int mt = 0; mt < 8; ++mt) {
                    frag_ab wf = wlds[(q * 4 + g) * 128 + mt * 16 + lc];
                    acc[mt] = __builtin_amdgcn_mfma_f32_16x16x32_bf16(wf, zf[q], acc[mt], 0, 0, 0);
                }
            }
            // C layout: feature(within half) = mt*16 + g*4 + r, node col = lc

            // --- bias fold (U blocks only; block-uniform branch) + absmax ---
            float mx = 0.f;
            if (half == 0) {
                #pragma unroll
                for (int mt = 0; mt < 8; ++mt) {
                    float4 bb = b1f4[mt * 4 + g];
                    acc[mt][0] += bb.x; acc[mt][1] += bb.y;
                    acc[mt][2] += bb.z; acc[mt][3] += bb.w;
                    #pragma unroll
                    for (int r = 0; r < 4; ++r)
                        mx = fmaxf(mx, fabsf(acc[mt][r]));
                }
            } else {
                #pragma unroll
                for (int mt = 0; mt < 8; ++mt)
                    #pragma unroll
                    for (int r = 0; r < 4; ++r)
                        mx = fmaxf(mx, fabsf(acc[mt][r]));
            }
            mx = fmaxf(mx, __shfl_xor(mx, 16));
            mx = fmaxf(mx, __shfl_xor(mx, 32));
            mx = fmaxf(mx, 1e-12f);
            const float ainv = 127.0f / mx;

            // --- quantize + store this half's 128 B row segment ---
            unsigned char* urow = UVq + (size_t)node * 256 + roff;
            #pragma unroll
            for (int mt = 0; mt < 8; ++mt) {
                unsigned q0 = (unsigned)__builtin_fmaf(acc[mt][0], ainv, 128.5f);
                unsigned q1 = (unsigned)__builtin_fmaf(acc[mt][1], ainv, 128.5f);
                unsigned q2 = (unsigned)__builtin_fmaf(acc[mt][2], ainv, 128.5f);
                unsigned q3 = (unsigned)__builtin_fmaf(acc[mt][3], ainv, 128.5f);
                *(unsigned*)&urow[mt * 16 + g * 4] = q0 | (q1 << 8) | (q2 << 16) | (q3 << 24);
            }
            if (g == 0)
                scales[node * 2 + half] = mx * (1.0f / 127.0f);
        }
        bslot += PC_BLOCKS;
    }
}

// ---------------------------------------------------------------------------
// Kernel 2: per-edge score = relu(aU*(u-128) + aV*(v-128)) . W2 + b2
// UNCHANGED (measured structure-invariant at the gather ceiling).
// ---------------------------------------------------------------------------
__device__ inline float dq4(unsigned uq, unsigned vq, float aU, float aV,
                            float k, float4 w, float acc) {
    #pragma unroll
    for (int b = 0; b < 4; ++b) {
        float uf = (float)((uq >> (8 * b)) & 0xffu);
        float vf = (float)((vq >> (8 * b)) & 0xffu);
        float h  = __builtin_fmaf(aU, uf, __builtin_fmaf(aV, vf, k));
        h = fmaxf(h, 0.f);
        float wv = (b == 0) ? w.x : (b == 1) ? w.y : (b == 2) ? w.z : w.w;
        acc = __builtin_fmaf(h, wv, acc);
    }
    return acc;
}

__global__ __launch_bounds__(256) void edge_score(
    const int* __restrict__ ei, const unsigned char* __restrict__ UVq,
    const float* __restrict__ scales, const float* __restrict__ W2,
    const float* __restrict__ B2, float* __restrict__ out)
{
    const int t = threadIdx.x;
    const int g = t & 7;
    const int slot = t >> 3;
    const int e0 = blockIdx.x * 64 + slot;
    const int e1 = e0 + 32;

    const float4* W24 = (const float4*)W2;
    const float4 w0 = W24[g * 4 + 0];
    const float4 w1 = W24[g * 4 + 1];
    const float4 w2 = W24[g * 4 + 2];
    const float4 w3 = W24[g * 4 + 3];

    const int s0 = ei[e0];
    const int d0 = ei[N_EDGES + e0];
    const int s1 = ei[e1];
    const int d1 = ei[N_EDGES + e1];

    // 16 B/lane x 8 lanes = one 128 B row-half per edge side (1 dwordx4 each)
    const uint4 u0 = *(const uint4*)(UVq + (size_t)s0 * 256 + g * 16);
    const uint4 v0 = *(const uint4*)(UVq + (size_t)d0 * 256 + 128 + g * 16);
    const uint4 u1 = *(const uint4*)(UVq + (size_t)s1 * 256 + g * 16);
    const uint4 v1 = *(const uint4*)(UVq + (size_t)d1 * 256 + 128 + g * 16);
    const float aU0 = scales[s0 * 2];
    const float aV0 = scales[d0 * 2 + 1];
    const float aU1 = scales[s1 * 2];
    const float aV1 = scales[d1 * 2 + 1];

    const float k0 = -128.f * (aU0 + aV0);
    const float k1 = -128.f * (aU1 + aV1);

    float A = 0.f, B = 0.f;
    A = dq4(u0.x, v0.x, aU0, aV0, k0, w0, A);
    A = dq4(u0.y, v0.y, aU0, aV0, k0, w1, A);
    A = dq4(u0.z, v0.z, aU0, aV0, k0, w2, A);
    A = dq4(u0.w, v0.w, aU0, aV0, k0, w3, A);

    B = dq4(u1.x, v1.x, aU1, aV1, k1, w0, B);
    B = dq4(u1.y, v1.y, aU1, aV1, k1, w1, B);
    B = dq4(u1.z, v1.z, aU1, aV1, k1, w2, B);
    B = dq4(u1.w, v1.w, aU1, aV1, k1, w3, B);

    float sa = A;
    float sb = B;
    sa += __shfl_xor(sa, 1, 8);
    sa += __shfl_xor(sa, 2, 8);
    sa += __shfl_xor(sa, 4, 8);
    sb += __shfl_xor(sb, 1, 8);
    sb += __shfl_xor(sb, 2, 8);
    sb += __shfl_xor(sb, 4, 8);

    if (g == 0) {
        float bb = B2[0];
        out[e0] = sa + bb;
        out[e1] = sb + bb;
    }
}

extern "C" void kernel_launch(void* const* d_in, const int* in_sizes, int n_in,
                              void* d_out, int out_size, void* d_ws, size_t ws_size,
                              hipStream_t stream) {
    const float* z  = (const float*)d_in[0];
    const int*   ei = (const int*)d_in[1];
    const float* W1 = (const float*)d_in[2];
    const float* b1 = (const float*)d_in[3];
    const float* W2 = (const float*)d_in[4];
    const float* b2 = (const float*)d_in[5];
    float* out = (float*)d_out;

    unsigned char* UVq = (unsigned char*)d_ws;                       // 25.6 MB
    float* scales = (float*)(UVq + (size_t)N_NODES * 256);           // 800 KB (U,V scale pairs)
    unsigned short* zbf = (unsigned short*)(scales + 2 * N_NODES);   // 25.6 MB bf16 z

    zcvt<<<12500, 256, 0, stream>>>((const float4*)z, (uint2*)zbf);
    precompute_uv_mfma<<<PC_BLOCKS, 256, 0, stream>>>(zbf, W1, b1, UVq, scales);
    edge_score<<<N_EDGES / 64, 256, 0, stream>>>(ei, UVq, scales, W2, b2, out);
}

// Round 12
// 143.999 us; speedup vs baseline: 1.0522x; 1.0522x over previous
//
#include <hip/hip_runtime.h>
#include <hip/hip_bf16.h>

#define N_NODES 100000
#define N_EDGES 800000
#define HIDDEN 128
#define NGROUPS 6250            // 100000 / 16 nodes per wave-group
#define PC_BLOCKS 512           // 2 blocks/CU (64 KB LDS each), 4 waves/block
#define PC_STRIDE 2048          // PC_BLOCKS * 4 waves

typedef short frag_ab __attribute__((ext_vector_type(8)));   // 8 x bf16
typedef float frag_cd __attribute__((ext_vector_type(4)));   // 4 x f32

// round-to-nearest-even fp32 -> bf16 (scalar)
__device__ inline unsigned short f2b(float f) {
    union { float f; unsigned u; } x; x.f = f;
    return (unsigned short)((x.u + 0x7fffu + ((x.u >> 16) & 1u)) >> 16);
}

// packed pair fp32 -> bf16x2 (v_cvt_pk_bf16_f32 on gfx950)
__device__ inline unsigned pk2(float x, float y) {
    union { __hip_bfloat162 h; unsigned u; } c;
    c.h = __float22bfloat162_rn(make_float2(x, y));
    return c.u;
}

// ---------------------------------------------------------------------------
// Kernel 0: transpose+convert W1 (256x128 fp32) -> Bt[256][128] bf16, k-contig.
// ---------------------------------------------------------------------------
__global__ __launch_bounds__(256) void transpose_w1(
    const float* __restrict__ W1, unsigned short* __restrict__ Bt)
{
    const int t  = threadIdx.x;
    const int nc = blockIdx.x * 4 + (t >> 6);
    const int k2 = (t & 63) * 2;
    const int col  = nc & 127;
    const int roff = (nc >= 128) ? 128 : 0;
    float f0 = W1[(size_t)(roff + k2)     * HIDDEN + col];
    float f1 = W1[(size_t)(roff + k2 + 1) * HIDDEN + col];
    *(unsigned*)(Bt + (size_t)nc * HIDDEN + k2) = (unsigned)f2b(f0) | ((unsigned)f2b(f1) << 16);
}

// ---------------------------------------------------------------------------
// Kernel 1 (MFMA GEMM): UV = z @ [W1src|W1dst] + [b1|0] -> uint8 + row scales.
// R21 = EXACT R16 (best measured wall 142.69 us; tied with R14's 142.68).
// Rationale: R17-R20 proved the wall is precompute-INSENSITIVE below ~45 us
// (occupancy 8->20 waves/CU and zcvt pre-conversion all moved the wall by
// less than +-4 us session noise, zcvt net-negative). Reverting to the
// measured-best structure: wave-autonomous (one wave owns 16 nodes x 256
// features), W staged once to 64 KB LDS chunk-major (single barrier),
// z register-direct with cross-group issue-early prefetch, in-lane absmax,
// zero steady-state barriers. Known spill-free (FETCH/WRITE ~25 MB).
// ---------------------------------------------------------------------------
__global__ __launch_bounds__(256) void precompute_uv_mfma(
    const float* __restrict__ z, const unsigned short* __restrict__ Bt,
    const float* __restrict__ b1, unsigned char* __restrict__ UVq,
    float* __restrict__ scales)
{
    __shared__ unsigned short smem[4096 * 8];        // 64 KB: Bt chunk-major [s][row]
    const int t = threadIdx.x;
    const int lane = t & 63;
    const int w = t >> 6;
    const int g  = lane >> 4;
    const int lc = lane & 15;

    // --- one-time stage: Bt (64 KB) -> LDS. Thread t copies row t's 16
    //     chunks; dst frag = s*256 + row -> contiguous 1 KB LDS writes. ---
    {
        const uint4* bt4 = (const uint4*)Bt;
        uint4* s4 = (uint4*)smem;
        #pragma unroll
        for (int k = 0; k < 16; ++k)
            s4[k * 256 + t] = bt4[t * 16 + k];       // row = t, s = k
    }
    __syncthreads();                                  // the only barrier

    const float4* zbase = (const float4*)z;
    const float4* b1f4  = (const float4*)b1;
    const frag_ab* wlds = (const frag_ab*)smem;

    int gid = blockIdx.x * 4 + w;                     // < 2048 <= NGROUPS
    float4 cur[8];
    {   // prologue z load: lane (g,lc) reads z[gid*16+lc][q*32+g*8 .. +7]
        const float4* zrow = zbase + (size_t)(gid * 16 + lc) * 32;
        #pragma unroll
        for (int i = 0; i < 8; ++i)
            cur[i] = zrow[(i >> 1) * 8 + g * 2 + (i & 1)];
    }

    while (true) {
        // --- pack current z -> bf16 fragments ---
        frag_ab zf[4];
        #pragma unroll
        for (int q = 0; q < 4; ++q) {
            union { unsigned u[4]; frag_ab f; } pk;
            pk.u[0] = pk2(cur[q * 2].x,     cur[q * 2].y);
            pk.u[1] = pk2(cur[q * 2].z,     cur[q * 2].w);
            pk.u[2] = pk2(cur[q * 2 + 1].x, cur[q * 2 + 1].y);
            pk.u[3] = pk2(cur[q * 2 + 1].z, cur[q * 2 + 1].w);
            zf[q] = pk.f;
        }

        // --- issue next group's z loads (consumed after the K-loop) ---
        const int nxt = gid + PC_STRIDE;
        const bool have = (nxt < NGROUPS);
        if (have) {
            const float4* zrow = zbase + (size_t)(nxt * 16 + lc) * 32;
            #pragma unroll
            for (int i = 0; i < 8; ++i)
                cur[i] = zrow[(i >> 1) * 8 + g * 2 + (i & 1)];
        }

        // --- K loop: 64 ds_read_b128 + 64 MFMA (A = W from LDS, B = zf) ---
        frag_cd acc[16];
        #pragma unroll
        for (int mt = 0; mt < 16; ++mt)
            acc[mt] = (frag_cd){0.f, 0.f, 0.f, 0.f};
        #pragma unroll
        for (int q = 0; q < 4; ++q) {
            #pragma unroll
            for (int mt = 0; mt < 16; ++mt) {
                frag_ab wf = wlds[(q * 4 + g) * 256 + mt * 16 + lc];
                acc[mt] = __builtin_amdgcn_mfma_f32_16x16x32_bf16(wf, zf[q], acc[mt], 0, 0, 0);
            }
        }
        // C layout: feature = mt*16 + g*4 + r, node col = lc

        // --- bias fold (U half) + per-node per-half absmax ---
        float mxU = 0.f, mxV = 0.f;
        #pragma unroll
        for (int mt = 0; mt < 8; ++mt) {
            float4 bb = b1f4[mt * 4 + g];
            acc[mt][0] += bb.x; acc[mt][1] += bb.y;
            acc[mt][2] += bb.z; acc[mt][3] += bb.w;
            #pragma unroll
            for (int r = 0; r < 4; ++r)
                mxU = fmaxf(mxU, fabsf(acc[mt][r]));
        }
        #pragma unroll
        for (int mt = 8; mt < 16; ++mt)
            #pragma unroll
            for (int r = 0; r < 4; ++r)
                mxV = fmaxf(mxV, fabsf(acc[mt][r]));

        mxU = fmaxf(mxU, __shfl_xor(mxU, 16));
        mxU = fmaxf(mxU, __shfl_xor(mxU, 32));
        mxV = fmaxf(mxV, __shfl_xor(mxV, 16));
        mxV = fmaxf(mxV, __shfl_xor(mxV, 32));
        mxU = fmaxf(mxU, 1e-12f);
        mxV = fmaxf(mxV, 1e-12f);
        const float ainvU = 127.0f / mxU;
        const float ainvV = 127.0f / mxV;

        // --- quantize + store ---
        const int node = gid * 16 + lc;
        unsigned char* urow = UVq + (size_t)node * 256;
        #pragma unroll
        for (int mt = 0; mt < 16; ++mt) {
            const float ainv = (mt < 8) ? ainvU : ainvV;
            unsigned q0 = (unsigned)__builtin_fmaf(acc[mt][0], ainv, 128.5f);
            unsigned q1 = (unsigned)__builtin_fmaf(acc[mt][1], ainv, 128.5f);
            unsigned q2 = (unsigned)__builtin_fmaf(acc[mt][2], ainv, 128.5f);
            unsigned q3 = (unsigned)__builtin_fmaf(acc[mt][3], ainv, 128.5f);
            *(unsigned*)&urow[mt * 16 + g * 4] = q0 | (q1 << 8) | (q2 << 16) | (q3 << 24);
        }
        if (g == 0) {
            scales[node * 2 + 0] = mxU * (1.0f / 127.0f);
            scales[node * 2 + 1] = mxV * (1.0f / 127.0f);
        }

        if (!have) break;
        gid = nxt;
    }
}

// ---------------------------------------------------------------------------
// Kernel 2: per-edge score = relu(aU*(u-128) + aV*(v-128)) . W2 + b2
// UNCHANGED (measured structure-invariant at the gather ceiling).
// ---------------------------------------------------------------------------
__device__ inline float dq4(unsigned uq, unsigned vq, float aU, float aV,
                            float k, float4 w, float acc) {
    #pragma unroll
    for (int b = 0; b < 4; ++b) {
        float uf = (float)((uq >> (8 * b)) & 0xffu);
        float vf = (float)((vq >> (8 * b)) & 0xffu);
        float h  = __builtin_fmaf(aU, uf, __builtin_fmaf(aV, vf, k));
        h = fmaxf(h, 0.f);
        float wv = (b == 0) ? w.x : (b == 1) ? w.y : (b == 2) ? w.z : w.w;
        acc = __builtin_fmaf(h, wv, acc);
    }
    return acc;
}

__global__ __launch_bounds__(256) void edge_score(
    const int* __restrict__ ei, const unsigned char* __restrict__ UVq,
    const float* __restrict__ scales, const float* __restrict__ W2,
    const float* __restrict__ B2, float* __restrict__ out)
{
    const int t = threadIdx.x;
    const int g = t & 7;
    const int slot = t >> 3;
    const int e0 = blockIdx.x * 64 + slot;
    const int e1 = e0 + 32;

    const float4* W24 = (const float4*)W2;
    const float4 w0 = W24[g * 4 + 0];
    const float4 w1 = W24[g * 4 + 1];
    const float4 w2 = W24[g * 4 + 2];
    const float4 w3 = W24[g * 4 + 3];

    const int s0 = ei[e0];
    const int d0 = ei[N_EDGES + e0];
    const int s1 = ei[e1];
    const int d1 = ei[N_EDGES + e1];

    // 16 B/lane x 8 lanes = one 128 B row-half per edge side (1 dwordx4 each)
    const uint4 u0 = *(const uint4*)(UVq + (size_t)s0 * 256 + g * 16);
    const uint4 v0 = *(const uint4*)(UVq + (size_t)d0 * 256 + 128 + g * 16);
    const uint4 u1 = *(const uint4*)(UVq + (size_t)s1 * 256 + g * 16);
    const uint4 v1 = *(const uint4*)(UVq + (size_t)d1 * 256 + 128 + g * 16);
    const float aU0 = scales[s0 * 2];
    const float aV0 = scales[d0 * 2 + 1];
    const float aU1 = scales[s1 * 2];
    const float aV1 = scales[d1 * 2 + 1];

    const float k0 = -128.f * (aU0 + aV0);
    const float k1 = -128.f * (aU1 + aV1);

    float A = 0.f, B = 0.f;
    A = dq4(u0.x, v0.x, aU0, aV0, k0, w0, A);
    A = dq4(u0.y, v0.y, aU0, aV0, k0, w1, A);
    A = dq4(u0.z, v0.z, aU0, aV0, k0, w2, A);
    A = dq4(u0.w, v0.w, aU0, aV0, k0, w3, A);

    B = dq4(u1.x, v1.x, aU1, aV1, k1, w0, B);
    B = dq4(u1.y, v1.y, aU1, aV1, k1, w1, B);
    B = dq4(u1.z, v1.z, aU1, aV1, k1, w2, B);
    B = dq4(u1.w, v1.w, aU1, aV1, k1, w3, B);

    float sa = A;
    float sb = B;
    sa += __shfl_xor(sa, 1, 8);
    sa += __shfl_xor(sa, 2, 8);
    sa += __shfl_xor(sa, 4, 8);
    sb += __shfl_xor(sb, 1, 8);
    sb += __shfl_xor(sb, 2, 8);
    sb += __shfl_xor(sb, 4, 8);

    if (g == 0) {
        float bb = B2[0];
        out[e0] = sa + bb;
        out[e1] = sb + bb;
    }
}

extern "C" void kernel_launch(void* const* d_in, const int* in_sizes, int n_in,
                              void* d_out, int out_size, void* d_ws, size_t ws_size,
                              hipStream_t stream) {
    const float* z  = (const float*)d_in[0];
    const int*   ei = (const int*)d_in[1];
    const float* W1 = (const float*)d_in[2];
    const float* b1 = (const float*)d_in[3];
    const float* W2 = (const float*)d_in[4];
    const float* b2 = (const float*)d_in[5];
    float* out = (float*)d_out;

    unsigned char* UVq = (unsigned char*)d_ws;                       // 25.6 MB
    float* scales = (float*)(UVq + (size_t)N_NODES * 256);           // 800 KB (U,V scale pairs)
    unsigned short* Bt = (unsigned short*)(scales + 2 * N_NODES);    // 64 KB, 16B-aligned

    transpose_w1<<<64, 256, 0, stream>>>(W1, Bt);
    precompute_uv_mfma<<<PC_BLOCKS, 256, 0, stream>>>(z, Bt, b1, UVq, scales);
    edge_score<<<N_EDGES / 64, 256, 0, stream>>>(ei, UVq, scales, W2, b2, out);
}